// Round 8
// baseline (193.794 us; speedup 1.0000x reference)
//
#include <hip/hip_runtime.h>
#include <hip/hip_bf16.h>
#include <cmath>

#define B_   256
#define S_   100
#define D_   512
#define H_   8
#define HD_  64
#define BS_  (B_ * S_)                 // 25600 rows
#define OUT_ELEMS  (BS_ * D_)          // 13107200
#define ATTN_ELEMS (B_ * H_ * S_ * S_) // 20480000
#define DD_  (D_ * D_)                 // 262144

typedef __bf16 bf16x8 __attribute__((ext_vector_type(8)));
typedef float  f32x4  __attribute__((ext_vector_type(4)));

// ---------------------------------------------------------------------------
// helpers
// ---------------------------------------------------------------------------
__device__ __forceinline__ void gload16(const void* g, void* l) {
    __builtin_amdgcn_global_load_lds(
        (const __attribute__((address_space(1))) void*)g,
        (__attribute__((address_space(3))) void*)l, 16, 0, 0);
}

// ---------------------------------------------------------------------------
// LDS tiles, T2 both-sides XOR swizzle (rows of 128 B = 8 x 16B chunks).
// Staged linearly by global_load_lds; SOURCE chunk is XOR-permuted by row&7,
// ds_read applies the same XOR -> 2-way bank aliasing only (free).
// ---------------------------------------------------------------------------
// 128-row tile (16 KB), 256 threads: 4 gloads/thread (4 per wave).
__device__ __forceinline__ void stage_tile(const __hip_bfloat16* __restrict__ src,
                                           char* ldsTile, int t) {
    #pragma unroll
    for (int i = 0; i < 4; ++i) {
        const int ci  = i * 256 + t;           // 16B chunk index 0..1023
        const int row = ci >> 3;               // 0..127
        const int sc  = (ci & 7) ^ (row & 7);  // inverse-swizzled source chunk
        gload16(src + (size_t)row * D_ + sc * 8,
                ldsTile + ((i * 256 + (t & 192)) << 4));  // wave-uniform base
    }
}

// 64-row tile (8 KB), 256 threads: 2 gloads/thread.
__device__ __forceinline__ void stage_tile_h(const __hip_bfloat16* __restrict__ src,
                                             char* ldsTile, int t) {
    #pragma unroll
    for (int i = 0; i < 2; ++i) {
        const int ci  = i * 256 + t;           // 16B chunk index 0..511
        const int row = ci >> 3;               // 0..63
        const int sc  = (ci & 7) ^ (row & 7);
        gload16(src + (size_t)row * D_ + sc * 8,
                ldsTile + ((i * 256 + (t & 192)) << 4));
    }
}

// 128-row tile (16 KB), 512 threads: 2 gloads/thread.
__device__ __forceinline__ void stage_a512(const __hip_bfloat16* __restrict__ src,
                                           char* ldsTile, int t) {
    #pragma unroll
    for (int i = 0; i < 2; ++i) {
        const int ci  = i * 512 + t;           // 0..1023
        const int row = ci >> 3;               // 0..127
        const int sc  = (ci & 7) ^ (row & 7);
        gload16(src + (size_t)row * D_ + sc * 8,
                ldsTile + ((i * 512 + (t & 448)) << 4));
    }
}

// 64-row tile (8 KB), 512 threads: 1 gload/thread.
__device__ __forceinline__ void stage_b512(const __hip_bfloat16* __restrict__ src,
                                           char* ldsTile, int t) {
    const int row = t >> 3;                    // 0..63
    const int sc  = (t & 7) ^ (row & 7);
    gload16(src + (size_t)row * D_ + sc * 8,
            ldsTile + ((t & 448) << 4));
}

// ---------------------------------------------------------------------------
// z-fused compute (512 thr): buf = A (16 KB) + 3x B half-tiles (8 KB).
// Each wave: 32x32 quadrant for ALL 3 z. 24 MFMA per BK=64 step.
// ---------------------------------------------------------------------------
__device__ __forceinline__ void compute_fused512(const char* buf, int lane,
                                                 int wr, int wc,
                                                 f32x4 acc[3][2][2]) {
    const int frow = lane & 15;
    const int fk   = lane >> 4;
    #pragma unroll
    for (int kk = 0; kk < 2; ++kk) {
        const int ch = kk * 4 + fk;
        bf16x8 af[2];
        #pragma unroll
        for (int m = 0; m < 2; ++m) {
            const int row = wr + m * 16 + frow;
            af[m] = *(const bf16x8*)(buf + row * 128 + ((ch ^ (row & 7)) << 4));
        }
        bf16x8 bfr[3][2];
        #pragma unroll
        for (int z = 0; z < 3; ++z)
            #pragma unroll
            for (int n = 0; n < 2; ++n) {
                const int row = wc + n * 16 + frow;
                bfr[z][n] = *(const bf16x8*)(buf + 16384 + z * 8192
                                             + row * 128 + ((ch ^ (row & 7)) << 4));
            }
        __builtin_amdgcn_s_setprio(1);
        #pragma unroll
        for (int z = 0; z < 3; ++z)
            #pragma unroll
            for (int m = 0; m < 2; ++m)
                #pragma unroll
                for (int n = 0; n < 2; ++n)
                    acc[z][m][n] = __builtin_amdgcn_mfma_f32_16x16x32_bf16(
                        af[m], bfr[z][n], acc[z][m][n], 0, 0, 0);
        __builtin_amdgcn_s_setprio(0);
    }
}

// outproj compute (256 thr): A 128-row tile + B 64-row tile, 64x32 per wave.
__device__ __forceinline__ void compute_tile_h(const char* ldsA, const char* ldsB,
                                               int lane, int wr, int wc,
                                               f32x4 acc[4][2]) {
    const int frow = lane & 15;
    const int fk   = lane >> 4;
    #pragma unroll
    for (int kk = 0; kk < 2; ++kk) {
        const int ch = kk * 4 + fk;
        bf16x8 af[4], bfr[2];
        #pragma unroll
        for (int m = 0; m < 4; ++m) {
            const int row = wr + m * 16 + frow;
            af[m] = *(const bf16x8*)(ldsA + row * 128 + ((ch ^ (row & 7)) << 4));
        }
        #pragma unroll
        for (int n = 0; n < 2; ++n) {
            const int row = wc + n * 16 + frow;
            bfr[n] = *(const bf16x8*)(ldsB + row * 128 + ((ch ^ (row & 7)) << 4));
        }
        __builtin_amdgcn_s_setprio(1);
        #pragma unroll
        for (int m = 0; m < 4; ++m)
            #pragma unroll
            for (int n = 0; n < 2; ++n)
                acc[m][n] = __builtin_amdgcn_mfma_f32_16x16x32_bf16(
                    af[m], bfr[n], acc[m][n], 0, 0, 0);
        __builtin_amdgcn_s_setprio(0);
    }
}

// ---------------------------------------------------------------------------
// Kernel: z-FUSED QKV projection, T4 counted-vmcnt 3-deep pipeline.
//   One block: Q,K,V for a (128r x 64c) tile. 512 thr / 8 waves.
//   LDS 120 KB (3 x (A 16K + 3x B 8K)); stages kt+1,kt+2 in flight across
//   barriers (vmcnt(10) steady; per wave per stage = 2 A + 3 B gloads).
//   RAW: counted vmcnt + barrier-1.  WAR: lgkmcnt(0) + barrier-2 precede
//   the stage issue, and gload_lds LDS-writes land only after issue.
// ---------------------------------------------------------------------------
__global__ __launch_bounds__(512) void qkv_gemm(
    const __hip_bfloat16* __restrict__ apos,
    const __hip_bfloat16* __restrict__ wall,   // Wq|Wk|Wv|Wo bf16, D*D each
    const float* __restrict__ bq, const float* __restrict__ bk,
    const float* __restrict__ bv, const float* __restrict__ pv,
    __hip_bfloat16* __restrict__ qkv)          // q|k|v, OUT_ELEMS each
{
    __shared__ __align__(16) char lds[3][40960];      // [buf][A | B0 B1 B2]
    const int t    = threadIdx.x;
    const int r0   = blockIdx.x * 128, c0 = blockIdx.y * 64;
    const int lane = t & 63, wid = t >> 6;
    const int wr   = (wid >> 1) << 5;          // 0,32,64,96
    const int wc   = (wid & 1) << 5;           // 0,32

    f32x4 acc[3][2][2] = {};

    const __hip_bfloat16* Ab = apos + (size_t)r0 * D_;

    // prologue: stage kt = 0,1,2  (15 loads/wave in flight)
    #pragma unroll
    for (int p = 0; p < 3; ++p) {
        stage_a512(Ab + p * 64, lds[p], t);
        #pragma unroll
        for (int z = 0; z < 3; ++z)
            stage_b512(wall + (size_t)z * DD_ + (size_t)c0 * D_ + p * 64,
                       lds[p] + 16384 + z * 8192, t);
    }

    #pragma unroll
    for (int kt = 0; kt < 8; ++kt) {
        if (kt <= 5)      asm volatile("s_waitcnt vmcnt(10)" ::: "memory");
        else if (kt == 6) asm volatile("s_waitcnt vmcnt(5)"  ::: "memory");
        else              asm volatile("s_waitcnt vmcnt(0)"  ::: "memory");
        __builtin_amdgcn_s_barrier();
        __builtin_amdgcn_sched_barrier(0);     // ds_reads stay below barrier
        compute_fused512(lds[kt % 3], lane, wr, wc, acc);
        asm volatile("s_waitcnt lgkmcnt(0)" ::: "memory");
        __builtin_amdgcn_s_barrier();
        __builtin_amdgcn_sched_barrier(0);     // stage stays below barrier
        if (kt + 3 < 8) {
            stage_a512(Ab + (kt + 3) * 64, lds[kt % 3], t);
            #pragma unroll
            for (int z = 0; z < 3; ++z)
                stage_b512(wall + (size_t)z * DD_ + (size_t)c0 * D_ + (kt + 3) * 64,
                           lds[kt % 3] + 16384 + z * 8192, t);
        }
    }

    // epilogue: +bias (−pv for V), scatter bf16 into [B,H,S,HD]
    const int fcol = lane & 15, fq = lane >> 4;
    #pragma unroll
    for (int z = 0; z < 3; ++z) {
        const float* bias = (z == 0) ? bq : (z == 1) ? bk : bv;
        __hip_bfloat16* outz = qkv + (size_t)z * OUT_ELEMS;
        #pragma unroll
        for (int n = 0; n < 2; ++n) {
            const int c  = c0 + wc + n * 16 + fcol;
            const float bi = bias[c];
            const int h = c >> 6, hd = c & 63;
            #pragma unroll
            for (int m = 0; m < 2; ++m) {
                const int rbase = r0 + wr + m * 16 + fq * 4;
                #pragma unroll
                for (int r = 0; r < 4; ++r) {
                    const int rowg = rbase + r;
                    const int b = rowg / S_;
                    const int s = rowg - b * S_;
                    float v = acc[z][m][n][r] + bi;
                    if (z == 2) v -= pv[s * D_ + c];
                    outz[(((size_t)b * H_ + h) * S_ + s) * HD_ + hd] =
                        __float2bfloat16(v);
                }
            }
        }
    }
}

// ---------------------------------------------------------------------------
// Kernel: output projection, same T4 pipeline. 256 thr; LDS 72 KB -> 2/CU.
//   Per wave per stage = 4 A + 2 B gloads -> vmcnt(12) steady.
// ---------------------------------------------------------------------------
__global__ __launch_bounds__(256) void outproj_gemm(
    const __hip_bfloat16* __restrict__ ctx,    // [BS][D] bf16 row-major
    const __hip_bfloat16* __restrict__ Wo,     // bf16 [D][D]
    const float* __restrict__ bo,
    float* __restrict__ out)                   // [BS][D] fp32
{
    __shared__ __align__(16) char lds[3][24576];      // [buf][A 16K | B 8K]
    const int t    = threadIdx.x;
    const int r0   = blockIdx.x * 128, c0 = blockIdx.y * 64;
    const int lane = t & 63, wid = t >> 6;
    const int wr   = (wid >> 1) << 6, wc = (wid & 1) << 5;

    f32x4 acc[4][2] = {};

    const __hip_bfloat16* Ab = ctx + (size_t)r0 * D_;
    const __hip_bfloat16* Bb = Wo  + (size_t)c0 * D_;

    #pragma unroll
    for (int p = 0; p < 3; ++p) {
        stage_tile(Ab + p * 64, lds[p], t);
        stage_tile_h(Bb + p * 64, lds[p] + 16384, t);
    }

    #pragma unroll
    for (int kt = 0; kt < 8; ++kt) {
        if (kt <= 5)      asm volatile("s_waitcnt vmcnt(12)" ::: "memory");
        else if (kt == 6) asm volatile("s_waitcnt vmcnt(6)"  ::: "memory");
        else              asm volatile("s_waitcnt vmcnt(0)"  ::: "memory");
        __builtin_amdgcn_s_barrier();
        __builtin_amdgcn_sched_barrier(0);
        compute_tile_h(lds[kt % 3], lds[kt % 3] + 16384, lane, wr, wc, acc);
        asm volatile("s_waitcnt lgkmcnt(0)" ::: "memory");
        __builtin_amdgcn_s_barrier();
        __builtin_amdgcn_sched_barrier(0);
        if (kt + 3 < 8) {
            stage_tile(Ab + (kt + 3) * 64, lds[kt % 3], t);
            stage_tile_h(Bb + (kt + 3) * 64, lds[kt % 3] + 16384, t);
        }
    }

    const int fcol = lane & 15, fq = lane >> 4;
    #pragma unroll
    for (int n = 0; n < 2; ++n) {
        const int c  = c0 + wc + n * 16 + fcol;
        const float bi = bo[c];
        #pragma unroll
        for (int m = 0; m < 4; ++m) {
            const int rbase = r0 + wr + m * 16 + fq * 4;
            #pragma unroll
            for (int r = 0; r < 4; ++r) {
                const int rowg = rbase + r;
                out[(size_t)rowg * D_ + c] = acc[m][n][r] + bi;
            }
        }
    }
}

// ---------------------------------------------------------------------------
// Kernel: MFMA attention (unchanged — verified; at its HBM floor ~29 us).
// ---------------------------------------------------------------------------
__global__ __launch_bounds__(256) void attn_mfma(
    const __hip_bfloat16* __restrict__ qkv,    // q|k|v [B,H,S,HD] bf16
    float* __restrict__ attn_out,              // [B,H,S,S] fp32
    __hip_bfloat16* __restrict__ ctx,          // [BS][D] bf16
    const float* __restrict__ td_ptr)
{
    __shared__ __align__(16) __hip_bfloat16 Vt[2][64][136];  // V^T per head
    __shared__ __align__(16) __hip_bfloat16 Pl[4][16][136];  // per-wave P
    __shared__ float dec[128];

    const int t    = threadIdx.x;
    const int lane = t & 63, wid = t >> 6;
    const int c    = lane & 15, g4 = lane >> 4;
    const int bh0  = blockIdx.x * 2;

    if (t < 128)
        dec[t] = (t < S_) ? 0.125f * powf(td_ptr[0], (float)(S_ - 1 - t)) : 0.f;

    // ---- stage V transposed for both heads (waves 0,1 -> head0; 2,3 -> head1)
    {
        const int h = wid >> 1;
        const int k = ((wid & 1) << 6) + lane;
        if (k < S_) {
            const __hip_bfloat16* vr = qkv + 2 * (size_t)OUT_ELEMS
                                     + (size_t)(bh0 + h) * (S_ * HD_)
                                     + (size_t)k * HD_;
            #pragma unroll
            for (int j8 = 0; j8 < 8; ++j8) {
                uint4 u = *(const uint4*)(vr + j8 * 8);
                const __hip_bfloat16* e = (const __hip_bfloat16*)&u;
                #pragma unroll
                for (int ee = 0; ee < 8; ++ee)
                    Vt[h][j8 * 8 + ee][k] = e[ee];          // 2B writes, ~2-way
            }
        }
        // zero pad keys 100..135 (so P(=0) x pad never makes NaN)
        for (int idx = t; idx < 2 * 64 * 9; idx += 256) {
            const int hh  = idx / 576;
            const int rem = idx - hh * 576;
            const int d   = rem / 9, c8 = rem - d * 9;
            *(double*)((char*)&Vt[hh][d][100] + c8 * 8) = 0.0;
        }
    }
    // zero this wave's P pad (keys 112..127) once
    *(double*)&Pl[wid][c][112 + 4 * g4] = 0.0;
    __syncthreads();

    // per-lane decay registers: key = 16*kt + 4*g4 + r
    float decr[7][4];
    #pragma unroll
    for (int kt = 0; kt < 7; ++kt)
        #pragma unroll
        for (int r = 0; r < 4; ++r)
            decr[kt][r] = dec[16 * kt + 4 * g4 + r];

    // ---- work items: 14 q-tiles (2 heads x 7), waves take (4,4,3,3)
    for (int item = wid; item < 14; item += 4) {
        const int hh = item / 7;
        const int qt = item - hh * 7;
        const int bh = bh0 + hh;
        const __hip_bfloat16* Qb = qkv + (size_t)bh * (S_ * HD_);
        const __hip_bfloat16* Kb = qkv + (size_t)OUT_ELEMS + (size_t)bh * (S_ * HD_);

        // B-operand fragments: Q rows (col=q), contiguous d
        const bf16x8 qf0 = *(const bf16x8*)(Qb + (16 * qt + c) * HD_ + 8 * g4);
        const bf16x8 qf1 = *(const bf16x8*)(Qb + (16 * qt + c) * HD_ + 32 + 8 * g4);

        // QK^T swapped: s[kt] covers keys 16kt+4g4+{0..3} at q-col c
        f32x4 s[7] = {};
        #pragma unroll
        for (int kt = 0; kt < 7; ++kt) {
            const bf16x8 kf0 = *(const bf16x8*)(Kb + (16 * kt + c) * HD_ + 8 * g4);
            const bf16x8 kf1 = *(const bf16x8*)(Kb + (16 * kt + c) * HD_ + 32 + 8 * g4);
            s[kt] = __builtin_amdgcn_mfma_f32_16x16x32_bf16(kf0, qf0, s[kt], 0, 0, 0);
            s[kt] = __builtin_amdgcn_mfma_f32_16x16x32_bf16(kf1, qf1, s[kt], 0, 0, 0);
        }

        // softmax over keys (fp32 decay+scale, index-mask, butterfly reduce)
        float m = -3.0e38f;
        #pragma unroll
        for (int kt = 0; kt < 7; ++kt)
            #pragma unroll
            for (int r = 0; r < 4; ++r) {
                float v = s[kt][r] * decr[kt][r];
                if (kt == 6 && (4 * g4 + r) >= 4) v = -3.0e38f;  // key >= 100
                s[kt][r] = v;
                m = fmaxf(m, v);
            }
        m = fmaxf(m, __shfl_xor(m, 16, 64));
        m = fmaxf(m, __shfl_xor(m, 32, 64));

        float sum = 0.f;
        #pragma unroll
        for (int kt = 0; kt < 7; ++kt)
            #pragma unroll
            for (int r = 0; r < 4; ++r) {
                const float p = __expf(s[kt][r] - m);
                s[kt][r] = p;
                sum += p;
            }
        sum += __shfl_xor(sum, 16, 64);
        sum += __shfl_xor(sum, 32, 64);
        const float rs = 1.0f / sum;

        // write attn (float4: 4 consecutive keys) + P to LDS (bf16)
        const int qg = 16 * qt + c;
        float* arow = attn_out + (size_t)bh * (S_ * S_) + (size_t)qg * S_;
        #pragma unroll
        for (int kt = 0; kt < 7; ++kt) {
            const float a0 = s[kt][0] * rs, a1 = s[kt][1] * rs;
            const float a2 = s[kt][2] * rs, a3 = s[kt][3] * rs;
            if (qg < S_ && (kt < 6 || g4 == 0))
                *(float4*)(arow + 16 * kt + 4 * g4) = make_float4(a0, a1, a2, a3);
            __align__(8) __hip_bfloat16 pb[4];
            pb[0] = __float2bfloat16(a0); pb[1] = __float2bfloat16(a1);
            pb[2] = __float2bfloat16(a2); pb[3] = __float2bfloat16(a3);
            *(double*)&Pl[wid][c][16 * kt + 4 * g4] = *(double*)pb;   // masked->0
        }

        // PV: ctx_tile[16 q][64 d] = P @ V   (A rows = q = c, B rows = Vt d-rows)
        f32x4 o[4] = {};
        #pragma unroll
        for (int kk = 0; kk < 4; ++kk) {
            const bf16x8 pf = *(const bf16x8*)&Pl[wid][c][32 * kk + 8 * g4];
            #pragma unroll
            for (int dt = 0; dt < 4; ++dt) {
                const bf16x8 vf = *(const bf16x8*)&Vt[hh][16 * dt + c][32 * kk + 8 * g4];
                o[dt] = __builtin_amdgcn_mfma_f32_16x16x32_bf16(pf, vf, o[dt], 0, 0, 0);
            }
        }

        // ctx store: row = q = 4g4+r (+16qt), col = d = 16dt+c
        const int b = bh >> 3, h = bh & 7;
        #pragma unroll
        for (int r = 0; r < 4; ++r) {
            const int q = 16 * qt + 4 * g4 + r;
            if (q < S_) {
                __hip_bfloat16* crow = ctx + (size_t)(b * S_ + q) * D_ + h * HD_ + c;
                #pragma unroll
                for (int dt = 0; dt < 4; ++dt)
                    crow[16 * dt] = __float2bfloat16(o[dt][r]);
            }
        }
    }
}

// ---------------------------------------------------------------------------
// Conversion / small kernels
// ---------------------------------------------------------------------------
__global__ __launch_bounds__(256) void conv_apos_kernel(
    const float* __restrict__ x, const float* __restrict__ pos,
    __hip_bfloat16* __restrict__ apos)
{
    const int i8   = (blockIdx.x * 256 + threadIdx.x) * 8;
    const int row  = i8 >> 9;
    const int prow = row % S_;
    const int pcol = i8 & 511;
    const float4* xv = (const float4*)(x + i8);
    const float4* pp = (const float4*)(pos + (size_t)prow * D_ + pcol);
    float4 a0 = xv[0], a1 = xv[1], p0 = pp[0], p1 = pp[1];
    __align__(16) __hip_bfloat16 o[8];
    o[0] = __float2bfloat16(a0.x + p0.x); o[1] = __float2bfloat16(a0.y + p0.y);
    o[2] = __float2bfloat16(a0.z + p0.z); o[3] = __float2bfloat16(a0.w + p0.w);
    o[4] = __float2bfloat16(a1.x + p1.x); o[5] = __float2bfloat16(a1.y + p1.y);
    o[6] = __float2bfloat16(a1.z + p1.z); o[7] = __float2bfloat16(a1.w + p1.w);
    *(uint4*)(apos + i8) = *(const uint4*)o;
}

__global__ __launch_bounds__(256) void conv_w_kernel(
    const float* __restrict__ Wq, const float* __restrict__ Wk,
    const float* __restrict__ Wv, const float* __restrict__ Wo,
    __hip_bfloat16* __restrict__ wall)
{
    const int z = blockIdx.y;
    const float* src = (z == 0) ? Wq : (z == 1) ? Wk : (z == 2) ? Wv : Wo;
    __hip_bfloat16* dst = wall + (size_t)z * DD_;
    const int i8 = (blockIdx.x * 256 + threadIdx.x) * 8;
    const float4* sv = (const float4*)(src + i8);
    float4 a0 = sv[0], a1 = sv[1];
    __align__(16) __hip_bfloat16 o[8];
    o[0] = __float2bfloat16(a0.x); o[1] = __float2bfloat16(a0.y);
    o[2] = __float2bfloat16(a0.z); o[3] = __float2bfloat16(a0.w);
    o[4] = __float2bfloat16(a1.x); o[5] = __float2bfloat16(a1.y);
    o[6] = __float2bfloat16(a1.z); o[7] = __float2bfloat16(a1.w);
    *(uint4*)(dst + i8) = *(const uint4*)o;
}

// pv[s][c] = sum_k pos[s][k] * Wv[c][k]   (fp32, 100x512)
__global__ __launch_bounds__(256) void posv_kernel(
    const float* __restrict__ pos, const float* __restrict__ Wv,
    float* __restrict__ pvout)
{
    const int idx = blockIdx.x * 256 + threadIdx.x;
    const int s = idx >> 9, c = idx & 511;
    const float4* pr = (const float4*)(pos + (size_t)s * D_);
    const float4* wr = (const float4*)(Wv + (size_t)c * D_);
    float a = 0.f;
    #pragma unroll 4
    for (int k = 0; k < D_ / 4; ++k) {
        float4 p = pr[k], w = wr[k];
        a = fmaf(p.x, w.x, a); a = fmaf(p.y, w.y, a);
        a = fmaf(p.z, w.z, a); a = fmaf(p.w, w.w, a);
    }
    pvout[idx] = a;
}

// ---------------------------------------------------------------------------
extern "C" void kernel_launch(void* const* d_in, const int* in_sizes, int n_in,
                              void* d_out, int out_size, void* d_ws, size_t ws_size,
                              hipStream_t stream) {
    (void)in_sizes; (void)n_in; (void)out_size; (void)ws_size;
    const float* x   = (const float*)d_in[0];
    const float* pos = (const float*)d_in[1];
    const float* td  = (const float*)d_in[2];
    const float* Wq  = (const float*)d_in[3];
    const float* bq  = (const float*)d_in[4];
    const float* Wk  = (const float*)d_in[5];
    const float* bk  = (const float*)d_in[6];
    const float* Wv  = (const float*)d_in[7];
    const float* bv  = (const float*)d_in[8];
    const float* Wo  = (const float*)d_in[9];
    const float* bo  = (const float*)d_in[10];

    float* out  = (float*)d_out;
    float* attn = out + (size_t)OUT_ELEMS;

    // ws layout (133.4 MB total):
    //   apos bf16 [BS][D]      @ 0          (26,214,400 B)
    //   q|k|v bf16 [B,H,S,HD]  @ 26214400   (78,643,200 B)
    //   ctx bf16 [BS][D]       @ 104857600  (26,214,400 B)
    //   W bf16 x4              @ 131072000  ( 2,097,152 B)
    //   pv fp32 [S][D]         @ 133169152  (   204,800 B)
    char* ws = (char*)d_ws;
    __hip_bfloat16* apos = (__hip_bfloat16*)ws;
    __hip_bfloat16* qkv  = (__hip_bfloat16*)(ws + 26214400);
    __hip_bfloat16* ctx  = (__hip_bfloat16*)(ws + 104857600);
    __hip_bfloat16* wall = (__hip_bfloat16*)(ws + 131072000);
    float*          pvb  = (float*)(ws + 133169152);

    conv_apos_kernel<<<OUT_ELEMS / 8 / 256, 256, 0, stream>>>(x, pos, apos);
    conv_w_kernel<<<dim3(DD_ / 8 / 256, 4), 256, 0, stream>>>(Wq, Wk, Wv, Wo, wall);
    posv_kernel<<<(S_ * D_) / 256, 256, 0, stream>>>(pos, Wv, pvb);

    qkv_gemm<<<dim3(BS_ / 128, D_ / 64), 512, 0, stream>>>(
        apos, wall, bq, bk, bv, pvb, qkv);
    attn_mfma<<<B_ * H_ / 2, 256, 0, stream>>>(qkv, attn, ctx, td);
    outproj_gemm<<<dim3(BS_ / 128, D_ / 64), 256, 0, stream>>>(
        ctx, wall + 3 * (size_t)DD_, bo, out);
}

// Round 10
// 180.621 us; speedup vs baseline: 1.0729x; 1.0729x over previous
//
#include <hip/hip_runtime.h>
#include <hip/hip_bf16.h>
#include <cmath>

#define B_   256
#define S_   100
#define D_   512
#define H_   8
#define HD_  64
#define BS_  (B_ * S_)                 // 25600 rows
#define OUT_ELEMS  (BS_ * D_)          // 13107200
#define ATTN_ELEMS (B_ * H_ * S_ * S_) // 20480000
#define DD_  (D_ * D_)                 // 262144

typedef __bf16 bf16x8 __attribute__((ext_vector_type(8)));
typedef float  f32x4  __attribute__((ext_vector_type(4)));

// ---------------------------------------------------------------------------
// helpers
// ---------------------------------------------------------------------------
__device__ __forceinline__ void gload16(const void* g, void* l) {
    __builtin_amdgcn_global_load_lds(
        (const __attribute__((address_space(1))) void*)g,
        (__attribute__((address_space(3))) void*)l, 16, 0, 0);
}

// ---------------------------------------------------------------------------
// LDS tiles, T2 both-sides XOR swizzle (rows of 128 B = 8 x 16B chunks).
// Staged linearly by global_load_lds; SOURCE chunk is XOR-permuted by row&7,
// ds_read applies the same XOR -> 2-way bank aliasing only (free).
// ---------------------------------------------------------------------------
// 128-row tile (16 KB), 256 threads: 4 chunks/thread.
__device__ __forceinline__ void stage_tile(const __hip_bfloat16* __restrict__ src,
                                           char* ldsTile, int t) {
    #pragma unroll
    for (int i = 0; i < 4; ++i) {
        const int ci  = i * 256 + t;           // 16B chunk index 0..1023
        const int row = ci >> 3;               // 0..127
        const int sc  = (ci & 7) ^ (row & 7);  // inverse-swizzled source chunk
        gload16(src + (size_t)row * D_ + sc * 8,
                ldsTile + ((i * 256 + (t & 192)) << 4));  // wave-uniform base
    }
}

// 64-row tile (8 KB), 256 threads: 2 chunks/thread.
__device__ __forceinline__ void stage_tile_h(const __hip_bfloat16* __restrict__ src,
                                             char* ldsTile, int t) {
    #pragma unroll
    for (int i = 0; i < 2; ++i) {
        const int ci  = i * 256 + t;           // 16B chunk index 0..511
        const int row = ci >> 3;               // 0..63
        const int sc  = (ci & 7) ^ (row & 7);
        gload16(src + (size_t)row * D_ + sc * 8,
                ldsTile + ((i * 256 + (t & 192)) << 4));
    }
}

// ---------------------------------------------------------------------------
// z-fused compute: buf = A tile (16 KB) + 3 B half-tiles (8 KB each).
// Each wave: 64x32 output quadrant for ALL 3 z. 48 MFMA per BK=64 step.
// ---------------------------------------------------------------------------
__device__ __forceinline__ void compute_fused(const char* buf, int lane,
                                              int wr, int wc,
                                              f32x4 acc[3][4][2]) {
    const int frow = lane & 15;
    const int fk   = lane >> 4;
    #pragma unroll
    for (int kk = 0; kk < 2; ++kk) {
        const int ch = kk * 4 + fk;
        bf16x8 af[4];
        #pragma unroll
        for (int m = 0; m < 4; ++m) {
            const int row = wr + m * 16 + frow;
            af[m] = *(const bf16x8*)(buf + row * 128 + ((ch ^ (row & 7)) << 4));
        }
        bf16x8 bfr[3][2];
        #pragma unroll
        for (int z = 0; z < 3; ++z)
            #pragma unroll
            for (int n = 0; n < 2; ++n) {
                const int row = wc + n * 16 + frow;
                bfr[z][n] = *(const bf16x8*)(buf + 16384 + z * 8192
                                             + row * 128 + ((ch ^ (row & 7)) << 4));
            }
        __builtin_amdgcn_s_setprio(1);
        #pragma unroll
        for (int z = 0; z < 3; ++z)
            #pragma unroll
            for (int m = 0; m < 4; ++m)
                #pragma unroll
                for (int n = 0; n < 2; ++n)
                    acc[z][m][n] = __builtin_amdgcn_mfma_f32_16x16x32_bf16(
                        af[m], bfr[z][n], acc[z][m][n], 0, 0, 0);
        __builtin_amdgcn_s_setprio(0);
    }
}

// outproj compute: A 128-row tile + B 64-row tile. 16 MFMA per BK=64 step.
__device__ __forceinline__ void compute_tile_h(const char* ldsA, const char* ldsB,
                                               int lane, int wr, int wc,
                                               f32x4 acc[4][2]) {
    const int frow = lane & 15;
    const int fk   = lane >> 4;
    #pragma unroll
    for (int kk = 0; kk < 2; ++kk) {
        const int ch = kk * 4 + fk;
        bf16x8 af[4], bfr[2];
        #pragma unroll
        for (int m = 0; m < 4; ++m) {
            const int row = wr + m * 16 + frow;
            af[m] = *(const bf16x8*)(ldsA + row * 128 + ((ch ^ (row & 7)) << 4));
        }
        #pragma unroll
        for (int n = 0; n < 2; ++n) {
            const int row = wc + n * 16 + frow;
            bfr[n] = *(const bf16x8*)(ldsB + row * 128 + ((ch ^ (row & 7)) << 4));
        }
        __builtin_amdgcn_s_setprio(1);
        #pragma unroll
        for (int m = 0; m < 4; ++m)
            #pragma unroll
            for (int n = 0; n < 2; ++n)
                acc[m][n] = __builtin_amdgcn_mfma_f32_16x16x32_bf16(
                    af[m], bfr[n], acc[m][n], 0, 0, 0);
        __builtin_amdgcn_s_setprio(0);
    }
}

// ---------------------------------------------------------------------------
// Kernel: z-FUSED QKV projection (R6-proven).  One block: Q,K,V for a
//   (128r x 64c) tile.  A (=apos) staged ONCE per K-step, reused by 3 MFMA
//   sets.  V subtracts pv = pos @ Wv^T (fp32).  256 thr / 4 waves;
//   LDS 80 KB (dbuf x (A 16K + 3x B 8K)) -> 2 blocks/CU.
// ---------------------------------------------------------------------------
__global__ __launch_bounds__(256) void qkv_gemm(
    const __hip_bfloat16* __restrict__ apos,
    const __hip_bfloat16* __restrict__ wall,   // Wq|Wk|Wv|Wo bf16, D*D each
    const float* __restrict__ bq, const float* __restrict__ bk,
    const float* __restrict__ bv, const float* __restrict__ pv,
    __hip_bfloat16* __restrict__ qkv)          // q|k|v, OUT_ELEMS each
{
    __shared__ __align__(16) char lds[2][40960];      // [buf][A | B0 B1 B2]
    const int t    = threadIdx.x;
    const int r0   = blockIdx.x * 128, c0 = blockIdx.y * 64;
    const int lane = t & 63, wid = t >> 6;
    const int wr   = (wid >> 1) << 6;          // 0 or 64
    const int wc   = (wid & 1) << 5;           // 0 or 32

    f32x4 acc[3][4][2] = {};

    const __hip_bfloat16* Ab = apos + (size_t)r0 * D_;

    // prologue: stage A + 3 B half-tiles for kt=0
    stage_tile(Ab, lds[0], t);
    #pragma unroll
    for (int z = 0; z < 3; ++z)
        stage_tile_h(wall + (size_t)z * DD_ + (size_t)c0 * D_,
                     lds[0] + 16384 + z * 8192, t);
    asm volatile("s_waitcnt vmcnt(0)" ::: "memory");
    __syncthreads();

    int cur = 0;
    for (int kt = 1; kt < 8; ++kt) {
        stage_tile(Ab + kt * 64, lds[cur ^ 1], t);
        #pragma unroll
        for (int z = 0; z < 3; ++z)
            stage_tile_h(wall + (size_t)z * DD_ + (size_t)c0 * D_ + kt * 64,
                         lds[cur ^ 1] + 16384 + z * 8192, t);
        compute_fused(lds[cur], lane, wr, wc, acc);
        asm volatile("s_waitcnt vmcnt(0)" ::: "memory");
        __syncthreads();
        cur ^= 1;
    }
    compute_fused(lds[cur], lane, wr, wc, acc);

    // epilogue: +bias (−pv for V), scatter bf16 into [B,H,S,HD]
    const int fcol = lane & 15, fq = lane >> 4;
    #pragma unroll
    for (int z = 0; z < 3; ++z) {
        const float* bias = (z == 0) ? bq : (z == 1) ? bk : bv;
        __hip_bfloat16* outz = qkv + (size_t)z * OUT_ELEMS;
        #pragma unroll
        for (int n = 0; n < 2; ++n) {
            const int c  = c0 + wc + n * 16 + fcol;
            const float bi = bias[c];
            const int h = c >> 6, hd = c & 63;
            #pragma unroll
            for (int m = 0; m < 4; ++m) {
                const int rbase = r0 + wr + m * 16 + fq * 4;
                #pragma unroll
                for (int r = 0; r < 4; ++r) {
                    const int rowg = rbase + r;
                    const int b = rowg / S_;
                    const int s = rowg - b * S_;
                    float v = acc[z][m][n][r] + bi;
                    if (z == 2) v -= pv[s * D_ + c];
                    outz[(((size_t)b * H_ + h) * S_ + s) * HD_ + hd] =
                        __float2bfloat16(v);
                }
            }
        }
    }
}

// ---------------------------------------------------------------------------
// Kernel: output projection (R6-proven). BM=128, BN=64; 48 KB dbuf -> 3/CU.
// ---------------------------------------------------------------------------
__global__ __launch_bounds__(256) void outproj_gemm(
    const __hip_bfloat16* __restrict__ ctx,    // [BS][D] bf16 row-major
    const __hip_bfloat16* __restrict__ Wo,     // bf16 [D][D]
    const float* __restrict__ bo,
    float* __restrict__ out)                   // [BS][D] fp32
{
    __shared__ __align__(16) char lds[2][24576];      // [buf][A 16K | B 8K]
    const int t    = threadIdx.x;
    const int r0   = blockIdx.x * 128, c0 = blockIdx.y * 64;
    const int lane = t & 63, wid = t >> 6;
    const int wr   = (wid >> 1) << 6, wc = (wid & 1) << 5;

    f32x4 acc[4][2] = {};

    const __hip_bfloat16* Ab = ctx + (size_t)r0 * D_;
    const __hip_bfloat16* Bb = Wo  + (size_t)c0 * D_;

    stage_tile(Ab, lds[0], t);
    stage_tile_h(Bb, lds[0] + 16384, t);
    asm volatile("s_waitcnt vmcnt(0)" ::: "memory");
    __syncthreads();

    int cur = 0;
    for (int kt = 1; kt < 8; ++kt) {
        stage_tile(Ab + kt * 64, lds[cur ^ 1], t);
        stage_tile_h(Bb + kt * 64, lds[cur ^ 1] + 16384, t);
        compute_tile_h(lds[cur], lds[cur] + 16384, lane, wr, wc, acc);
        asm volatile("s_waitcnt vmcnt(0)" ::: "memory");
        __syncthreads();
        cur ^= 1;
    }
    compute_tile_h(lds[cur], lds[cur] + 16384, lane, wr, wc, acc);

    const int fcol = lane & 15, fq = lane >> 4;
    #pragma unroll
    for (int n = 0; n < 2; ++n) {
        const int c  = c0 + wc + n * 16 + fcol;
        const float bi = bo[c];
        #pragma unroll
        for (int m = 0; m < 4; ++m) {
            const int rbase = r0 + wr + m * 16 + fq * 4;
            #pragma unroll
            for (int r = 0; r < 4; ++r) {
                const int rowg = rbase + r;
                out[(size_t)rowg * D_ + c] = acc[m][n][r] + bi;
            }
        }
    }
}

// ---------------------------------------------------------------------------
// Kernel: MFMA attention (unchanged — verified; at its HBM floor ~29 us).
// ---------------------------------------------------------------------------
__global__ __launch_bounds__(256) void attn_mfma(
    const __hip_bfloat16* __restrict__ qkv,    // q|k|v [B,H,S,HD] bf16
    float* __restrict__ attn_out,              // [B,H,S,S] fp32
    __hip_bfloat16* __restrict__ ctx,          // [BS][D] bf16
    const float* __restrict__ td_ptr)
{
    __shared__ __align__(16) __hip_bfloat16 Vt[2][64][136];  // V^T per head
    __shared__ __align__(16) __hip_bfloat16 Pl[4][16][136];  // per-wave P
    __shared__ float dec[128];

    const int t    = threadIdx.x;
    const int lane = t & 63, wid = t >> 6;
    const int c    = lane & 15, g4 = lane >> 4;
    const int bh0  = blockIdx.x * 2;

    if (t < 128)
        dec[t] = (t < S_) ? 0.125f * powf(td_ptr[0], (float)(S_ - 1 - t)) : 0.f;

    // ---- stage V transposed for both heads (waves 0,1 -> head0; 2,3 -> head1)
    {
        const int h = wid >> 1;
        const int k = ((wid & 1) << 6) + lane;
        if (k < S_) {
            const __hip_bfloat16* vr = qkv + 2 * (size_t)OUT_ELEMS
                                     + (size_t)(bh0 + h) * (S_ * HD_)
                                     + (size_t)k * HD_;
            #pragma unroll
            for (int j8 = 0; j8 < 8; ++j8) {
                uint4 u = *(const uint4*)(vr + j8 * 8);
                const __hip_bfloat16* e = (const __hip_bfloat16*)&u;
                #pragma unroll
                for (int ee = 0; ee < 8; ++ee)
                    Vt[h][j8 * 8 + ee][k] = e[ee];          // 2B writes, ~2-way
            }
        }
        // zero pad keys 100..135 (so P(=0) x pad never makes NaN)
        for (int idx = t; idx < 2 * 64 * 9; idx += 256) {
            const int hh  = idx / 576;
            const int rem = idx - hh * 576;
            const int d   = rem / 9, c8 = rem - d * 9;
            *(double*)((char*)&Vt[hh][d][100] + c8 * 8) = 0.0;
        }
    }
    // zero this wave's P pad (keys 112..127) once
    *(double*)&Pl[wid][c][112 + 4 * g4] = 0.0;
    __syncthreads();

    // per-lane decay registers: key = 16*kt + 4*g4 + r
    float decr[7][4];
    #pragma unroll
    for (int kt = 0; kt < 7; ++kt)
        #pragma unroll
        for (int r = 0; r < 4; ++r)
            decr[kt][r] = dec[16 * kt + 4 * g4 + r];

    // ---- work items: 14 q-tiles (2 heads x 7), waves take (4,4,3,3)
    for (int item = wid; item < 14; item += 4) {
        const int hh = item / 7;
        const int qt = item - hh * 7;
        const int bh = bh0 + hh;
        const __hip_bfloat16* Qb = qkv + (size_t)bh * (S_ * HD_);
        const __hip_bfloat16* Kb = qkv + (size_t)OUT_ELEMS + (size_t)bh * (S_ * HD_);

        // B-operand fragments: Q rows (col=q), contiguous d
        const bf16x8 qf0 = *(const bf16x8*)(Qb + (16 * qt + c) * HD_ + 8 * g4);
        const bf16x8 qf1 = *(const bf16x8*)(Qb + (16 * qt + c) * HD_ + 32 + 8 * g4);

        // QK^T swapped: s[kt] covers keys 16kt+4g4+{0..3} at q-col c
        f32x4 s[7] = {};
        #pragma unroll
        for (int kt = 0; kt < 7; ++kt) {
            const bf16x8 kf0 = *(const bf16x8*)(Kb + (16 * kt + c) * HD_ + 8 * g4);
            const bf16x8 kf1 = *(const bf16x8*)(Kb + (16 * kt + c) * HD_ + 32 + 8 * g4);
            s[kt] = __builtin_amdgcn_mfma_f32_16x16x32_bf16(kf0, qf0, s[kt], 0, 0, 0);
            s[kt] = __builtin_amdgcn_mfma_f32_16x16x32_bf16(kf1, qf1, s[kt], 0, 0, 0);
        }

        // softmax over keys (fp32 decay+scale, index-mask, butterfly reduce)
        float m = -3.0e38f;
        #pragma unroll
        for (int kt = 0; kt < 7; ++kt)
            #pragma unroll
            for (int r = 0; r < 4; ++r) {
                float v = s[kt][r] * decr[kt][r];
                if (kt == 6 && (4 * g4 + r) >= 4) v = -3.0e38f;  // key >= 100
                s[kt][r] = v;
                m = fmaxf(m, v);
            }
        m = fmaxf(m, __shfl_xor(m, 16, 64));
        m = fmaxf(m, __shfl_xor(m, 32, 64));

        float sum = 0.f;
        #pragma unroll
        for (int kt = 0; kt < 7; ++kt)
            #pragma unroll
            for (int r = 0; r < 4; ++r) {
                const float p = __expf(s[kt][r] - m);
                s[kt][r] = p;
                sum += p;
            }
        sum += __shfl_xor(sum, 16, 64);
        sum += __shfl_xor(sum, 32, 64);
        const float rs = 1.0f / sum;

        // write attn (float4: 4 consecutive keys) + P to LDS (bf16)
        const int qg = 16 * qt + c;
        float* arow = attn_out + (size_t)bh * (S_ * S_) + (size_t)qg * S_;
        #pragma unroll
        for (int kt = 0; kt < 7; ++kt) {
            const float a0 = s[kt][0] * rs, a1 = s[kt][1] * rs;
            const float a2 = s[kt][2] * rs, a3 = s[kt][3] * rs;
            if (qg < S_ && (kt < 6 || g4 == 0))
                *(float4*)(arow + 16 * kt + 4 * g4) = make_float4(a0, a1, a2, a3);
            __align__(8) __hip_bfloat16 pb[4];
            pb[0] = __float2bfloat16(a0); pb[1] = __float2bfloat16(a1);
            pb[2] = __float2bfloat16(a2); pb[3] = __float2bfloat16(a3);
            *(double*)&Pl[wid][c][16 * kt + 4 * g4] = *(double*)pb;   // masked->0
        }

        // PV: ctx_tile[16 q][64 d] = P @ V   (A rows = q = c, B rows = Vt d-rows)
        f32x4 o[4] = {};
        #pragma unroll
        for (int kk = 0; kk < 4; ++kk) {
            const bf16x8 pf = *(const bf16x8*)&Pl[wid][c][32 * kk + 8 * g4];
            #pragma unroll
            for (int dt = 0; dt < 4; ++dt) {
                const bf16x8 vf = *(const bf16x8*)&Vt[hh][16 * dt + c][32 * kk + 8 * g4];
                o[dt] = __builtin_amdgcn_mfma_f32_16x16x32_bf16(pf, vf, o[dt], 0, 0, 0);
            }
        }

        // ctx store: row = q = 4g4+r (+16qt), col = d = 16dt+c
        const int b = bh >> 3, h = bh & 7;
        #pragma unroll
        for (int r = 0; r < 4; ++r) {
            const int q = 16 * qt + 4 * g4 + r;
            if (q < S_) {
                __hip_bfloat16* crow = ctx + (size_t)(b * S_ + q) * D_ + h * HD_ + c;
                #pragma unroll
                for (int dt = 0; dt < 4; ++dt)
                    crow[16 * dt] = __float2bfloat16(o[dt][r]);
            }
        }
    }
}

// ---------------------------------------------------------------------------
// Conversion / small kernels
// ---------------------------------------------------------------------------
__global__ __launch_bounds__(256) void conv_apos_kernel(
    const float* __restrict__ x, const float* __restrict__ pos,
    __hip_bfloat16* __restrict__ apos)
{
    const int i8   = (blockIdx.x * 256 + threadIdx.x) * 8;
    const int row  = i8 >> 9;
    const int prow = row % S_;
    const int pcol = i8 & 511;
    const float4* xv = (const float4*)(x + i8);
    const float4* pp = (const float4*)(pos + (size_t)prow * D_ + pcol);
    float4 a0 = xv[0], a1 = xv[1], p0 = pp[0], p1 = pp[1];
    __align__(16) __hip_bfloat16 o[8];
    o[0] = __float2bfloat16(a0.x + p0.x); o[1] = __float2bfloat16(a0.y + p0.y);
    o[2] = __float2bfloat16(a0.z + p0.z); o[3] = __float2bfloat16(a0.w + p0.w);
    o[4] = __float2bfloat16(a1.x + p1.x); o[5] = __float2bfloat16(a1.y + p1.y);
    o[6] = __float2bfloat16(a1.z + p1.z); o[7] = __float2bfloat16(a1.w + p1.w);
    *(uint4*)(apos + i8) = *(const uint4*)o;
}

// Merged prep: y<4 -> W fp32->bf16 convert; y=4 -> pv = pos @ Wv^T (fp32).
__global__ __launch_bounds__(256) void prep_kernel(
    const float* __restrict__ Wq, const float* __restrict__ Wk,
    const float* __restrict__ Wv, const float* __restrict__ Wo,
    const float* __restrict__ pos,
    __hip_bfloat16* __restrict__ wall,
    float* __restrict__ pvout)
{
    const int y = blockIdx.y, bx = blockIdx.x, t = threadIdx.x;
    if (y < 4) {
        if (bx >= DD_ / 8 / 256) return;       // 128 blocks used
        const float* src = (y == 0) ? Wq : (y == 1) ? Wk : (y == 2) ? Wv : Wo;
        __hip_bfloat16* dst = wall + (size_t)y * DD_;
        const int i8 = (bx * 256 + t) * 8;
        const float4* sv = (const float4*)(src + i8);
        float4 a0 = sv[0], a1 = sv[1];
        __align__(16) __hip_bfloat16 o[8];
        o[0] = __float2bfloat16(a0.x); o[1] = __float2bfloat16(a0.y);
        o[2] = __float2bfloat16(a0.z); o[3] = __float2bfloat16(a0.w);
        o[4] = __float2bfloat16(a1.x); o[5] = __float2bfloat16(a1.y);
        o[6] = __float2bfloat16(a1.z); o[7] = __float2bfloat16(a1.w);
        *(uint4*)(dst + i8) = *(const uint4*)o;
    } else {
        const int idx = bx * 256 + t;          // < 51200
        const int s = idx >> 9, c = idx & 511;
        const float4* pr = (const float4*)(pos + (size_t)s * D_);
        const float4* wr = (const float4*)(Wv + (size_t)c * D_);
        float a = 0.f;
        #pragma unroll 4
        for (int k = 0; k < D_ / 4; ++k) {
            float4 p = pr[k], w = wr[k];
            a = fmaf(p.x, w.x, a); a = fmaf(p.y, w.y, a);
            a = fmaf(p.z, w.z, a); a = fmaf(p.w, w.w, a);
        }
        pvout[idx] = a;
    }
}

// ---------------------------------------------------------------------------
extern "C" void kernel_launch(void* const* d_in, const int* in_sizes, int n_in,
                              void* d_out, int out_size, void* d_ws, size_t ws_size,
                              hipStream_t stream) {
    (void)in_sizes; (void)n_in; (void)out_size; (void)ws_size;
    const float* x   = (const float*)d_in[0];
    const float* pos = (const float*)d_in[1];
    const float* td  = (const float*)d_in[2];
    const float* Wq  = (const float*)d_in[3];
    const float* bq  = (const float*)d_in[4];
    const float* Wk  = (const float*)d_in[5];
    const float* bk  = (const float*)d_in[6];
    const float* Wv  = (const float*)d_in[7];
    const float* bv  = (const float*)d_in[8];
    const float* Wo  = (const float*)d_in[9];
    const float* bo  = (const float*)d_in[10];

    float* out  = (float*)d_out;
    float* attn = out + (size_t)OUT_ELEMS;

    // ws layout (133.4 MB total):
    //   apos bf16 [BS][D]      @ 0          (26,214,400 B)
    //   q|k|v bf16 [B,H,S,HD]  @ 26214400   (78,643,200 B)
    //   ctx bf16 [BS][D]       @ 104857600  (26,214,400 B)
    //   W bf16 x4              @ 131072000  ( 2,097,152 B)
    //   pv fp32 [S][D]         @ 133169152  (   204,800 B)
    char* ws = (char*)d_ws;
    __hip_bfloat16* apos = (__hip_bfloat16*)ws;
    __hip_bfloat16* qkv  = (__hip_bfloat16*)(ws + 26214400);
    __hip_bfloat16* ctx  = (__hip_bfloat16*)(ws + 104857600);
    __hip_bfloat16* wall = (__hip_bfloat16*)(ws + 131072000);
    float*          pvb  = (float*)(ws + 133169152);

    conv_apos_kernel<<<OUT_ELEMS / 8 / 256, 256, 0, stream>>>(x, pos, apos);
    prep_kernel<<<dim3(200, 5), 256, 0, stream>>>(Wq, Wk, Wv, Wo, pos, wall, pvb);

    qkv_gemm<<<dim3(BS_ / 128, D_ / 64), 256, 0, stream>>>(
        apos, wall, bq, bk, bv, pvb, qkv);
    attn_mfma<<<B_ * H_ / 2, 256, 0, stream>>>(qkv, attn, ctx, td);
    outproj_gemm<<<dim3(BS_ / 128, D_ / 64), 256, 0, stream>>>(
        ctx, wall + 3 * (size_t)DD_, bo, out);
}